// Round 5
// baseline (316.924 us; speedup 1.0000x reference)
//
#include <hip/hip_runtime.h>
#include <cstddef>
#include <cstdint>

#define N_BATCH 32
#define WIDTH   512
#define T_DIM   2048
#define NB_CODE 1024
#define M_ROWS  65536
#define OUT_ELEMS 33554432
#define IDX_OFF  OUT_ELEMS
#define LOSS_OFF (OUT_ELEMS + M_ROWS)
#define PERP_OFF (LOSS_OFF + 1)
#define MARGIN   0.75f

typedef __attribute__((ext_vector_type(8))) short vshort8;
typedef __attribute__((ext_vector_type(4))) float vfloat4;

typedef __attribute__((address_space(1))) const uint32_t gu32_t;
typedef __attribute__((address_space(3))) uint32_t lu32_t;
static __device__ __forceinline__ void gload16(const void* g, void* l) {
    __builtin_amdgcn_global_load_lds((gu32_t*)g, (lu32_t*)l, 16, 0, 0);
}

static __device__ __forceinline__ unsigned short f2bf(float f) {
    uint32_t u = __float_as_uint(f);
    uint32_t r = (u + 0x7FFFu + ((u >> 16) & 1u)) >> 16;  // RNE
    return (unsigned short)r;
}

// ---------------- workspace layout (bytes) ----------------
// cbh       : [0, 1MB)             codebook hi bf16 [1024][512]
// cnorm     : [1MB, +4KB)
// cand      : [1MB+4KB, +256KB)
// idx_final : [1.5MB, +256KB)
// hist      : [2MB, +4KB)
// lossPart  : [2MB+4KB, +4KB)
// xT (bf16 [65536][512], 67MB) lives in the FIRST 67MB of d_out (scratch;
// overwritten by k_scatter afterwards).

// Fused: bf16 codebook + per-code norms + hist zeroing.
__global__ __launch_bounds__(128) void k_prep(const float* __restrict__ cb,
                                              unsigned short* __restrict__ cbh,
                                              float* __restrict__ cnorm,
                                              int* __restrict__ hist) {
    const int c = blockIdx.x, tid = threadIdx.x;
    float4 v = ((const float4*)(cb + (size_t)c * WIDTH))[tid];
    ushort4 h;
    h.x = f2bf(v.x); h.y = f2bf(v.y); h.z = f2bf(v.z); h.w = f2bf(v.w);
    ((ushort4*)(cbh + (size_t)c * WIDTH))[tid] = h;
    float s = v.x * v.x + v.y * v.y + v.z * v.z + v.w * v.w;
#pragma unroll
    for (int off = 32; off >= 1; off >>= 1) s += __shfl_xor(s, off, 64);
    __shared__ float sw[2];
    if ((tid & 63) == 0) sw[tid >> 6] = s;
    __syncthreads();
    if (tid == 0) { cnorm[c] = sw[0] + sw[1]; hist[c] = 0; }
}

// x [n][k][t] f32 -> xT [n][t][k] bf16. Coalesced read + LDS tile transpose.
__global__ __launch_bounds__(256) void k_xprep(const float* __restrict__ x,
                                               unsigned short* __restrict__ xT) {
    __shared__ float tile[32][33];
    const int t0 = blockIdx.x * 32, k0 = blockIdx.y * 32, n = blockIdx.z;
    const int tx = threadIdx.x, ty = threadIdx.y;  // 32 x 8
    const float* xb = x + ((size_t)n * WIDTH + k0) * T_DIM + t0;
#pragma unroll
    for (int j = 0; j < 32; j += 8)
        tile[ty + j][tx] = xb[(size_t)(ty + j) * T_DIM + tx];
    __syncthreads();
    unsigned short* ob = xT + ((size_t)n * T_DIM + t0) * WIDTH + k0;
#pragma unroll
    for (int j = 0; j < 32; j += 8)
        ob[(size_t)(ty + j) * WIDTH + tx] = f2bf(tile[tx][ty + j]);
}

// hh-screen argmin: 256 thr = 4 waves, 128 rows/block (32 rows/wave).
// 4-buffer LDS, depth-2 prefetch, counted vmcnt + raw s_barrier (no full drain).
__global__ __launch_bounds__(256, 2) void k_argmin(
    const unsigned short* __restrict__ xT, const unsigned short* __restrict__ cbh,
    const float* __restrict__ cnorm, uint32_t* __restrict__ cand) {
    __shared__ __align__(16) short lds[4][8192];   // 4 x 16KB
    __shared__ __align__(16) float cns[NB_CODE];

    const int tid = threadIdx.x;
    const int w = tid >> 6, l = tid & 63;
    const int l15 = l & 15, lg = l >> 4;

    const int rowl = l >> 3;                          // dest row within 8-row chunk
    const int srccol = ((l & 7) * 16) ^ (rowl << 4);  // pre-swizzled global source

#define STAGE(T) do {                                                               \
    const int cc_ = (T) >> 3, kc_ = (T) & 7;                                        \
    const char* gb_ = ((const char*)cbh) +                                          \
        (((size_t)(cc_ * 128 + w * 32 + rowl)) << 10) + kc_ * 128 + srccol;         \
    short* lb_ = &lds[(T) & 3][w * 2048];                                           \
    gload16(gb_,         lb_);                                                      \
    gload16(gb_ + 8192,  lb_ + 512);                                                \
    gload16(gb_ + 16384, lb_ + 1024);                                               \
    gload16(gb_ + 24576, lb_ + 1536);                                               \
} while (0)

    STAGE(0);
    STAGE(1);
    for (int i = tid; i < NB_CODE; i += 256) cns[i] = cnorm[i];
    __syncthreads();   // one full drain at startup: tiles 0,1 + cns visible

    // x fragments: 32 rows/wave from xT (contiguous 16B per frag)
    const int m0w = blockIdx.x * 128 + w * 32;
    const unsigned short* xb0 = xT + (size_t)(m0w + l15) * WIDTH;
    const unsigned short* xb1 = xb0 + 16 * WIDTH;
    vshort8 xh0[16], xh1[16];
#pragma unroll
    for (int ks = 0; ks < 16; ++ks) {
        const int k = ks * 32 + lg * 8;
        xh0[ks] = *(const vshort8*)(xb0 + k);
        xh1[ks] = *(const vshort8*)(xb1 + k);
    }

    // swizzled ds_read bases (shorts)
    const int mask = (l15 & 7) << 3;
    const int rd0 = l15 * 64 + ((lg * 8) ^ mask);
    const int rd1 = rd0 ^ 32;

    float b1a = 3.4e38f, b2a = 3.4e38f, b3a = 3.4e38f;
    float b1b = 3.4e38f, b2b = 3.4e38f, b3b = 3.4e38f;
    int i1a = 0, i2a = 0, i3a = 0, i1b = 0, i2b = 0, i3b = 0;

#define INS3(B1, B2, B3, I1, I2, I3, S, C) do {                               \
        const bool lt1 = (S) < B1, lt2 = (S) < B2, lt3 = (S) < B3;            \
        B3 = lt3 ? (lt2 ? B2 : (S)) : B3;  I3 = lt3 ? (lt2 ? I2 : (C)) : I3; \
        B2 = lt2 ? (lt1 ? B1 : (S)) : B2;  I2 = lt2 ? (lt1 ? I1 : (C)) : I2; \
        B1 = lt1 ? (S) : B1;               I1 = lt1 ? (C) : I1;              \
    } while (0)

    for (int cc = 0; cc < 8; ++cc) {
        vfloat4 acc0[8], acc1[8];
#pragma unroll
        for (int fm = 0; fm < 8; ++fm) {
            vfloat4 z = {0.f, 0.f, 0.f, 0.f};
            acc0[fm] = z; acc1[fm] = z;
        }

#pragma unroll
        for (int kc = 0; kc < 8; ++kc) {
            const int t = cc * 8 + kc;          // kc is compile-time; cc runtime
            // schedule: stage t+2, wait S(t) done (counted), barrier, compute buf t&3
            if (cc < 7 || kc <= 5) {
                STAGE(t + 2);
                asm volatile("s_waitcnt vmcnt(8)\ns_barrier" ::: "memory");
            } else if (kc == 6) {
                asm volatile("s_waitcnt vmcnt(4)\ns_barrier" ::: "memory");
            } else {
                asm volatile("s_waitcnt vmcnt(0)\ns_barrier" ::: "memory");
            }
            const short* lb = lds[t & 3];
            __builtin_amdgcn_s_setprio(1);
#pragma unroll
            for (int fm = 0; fm < 8; ++fm) {
                vshort8 a0 = *(const vshort8*)&lb[rd0 + fm * 1024];
                acc0[fm] = __builtin_amdgcn_mfma_f32_16x16x32_bf16(a0, xh0[kc * 2], acc0[fm], 0, 0, 0);
                acc1[fm] = __builtin_amdgcn_mfma_f32_16x16x32_bf16(a0, xh1[kc * 2], acc1[fm], 0, 0, 0);
            }
#pragma unroll
            for (int fm = 0; fm < 8; ++fm) {
                vshort8 a1 = *(const vshort8*)&lb[rd1 + fm * 1024];
                acc0[fm] = __builtin_amdgcn_mfma_f32_16x16x32_bf16(a1, xh0[kc * 2 + 1], acc0[fm], 0, 0, 0);
                acc1[fm] = __builtin_amdgcn_mfma_f32_16x16x32_bf16(a1, xh1[kc * 2 + 1], acc1[fm], 0, 0, 0);
            }
            __builtin_amdgcn_s_setprio(0);
            if (kc == 7) {
#pragma unroll
                for (int fm = 0; fm < 8; ++fm) {
                    const int cb0 = cc * 128 + fm * 16 + lg * 4;
                    vfloat4 cn = *(const vfloat4*)&cns[cb0];
#pragma unroll
                    for (int r = 0; r < 4; ++r) {
                        const int c = cb0 + r;
                        const float s0 = fmaf(-2.f, acc0[fm][r], cn[r]);
                        INS3(b1a, b2a, b3a, i1a, i2a, i3a, s0, c);
                        const float s1 = fmaf(-2.f, acc1[fm][r], cn[r]);
                        INS3(b1b, b2b, b3b, i1b, i2b, i3b, s1, c);
                    }
                }
            }
        }
    }

    // merge top-3 across the 4 lg groups (lane bits 4,5)
#pragma unroll
    for (int off = 16; off <= 32; off <<= 1) {
        float ob1 = __shfl_xor(b1a, off, 64), ob2 = __shfl_xor(b2a, off, 64), ob3 = __shfl_xor(b3a, off, 64);
        int oi1 = __shfl_xor(i1a, off, 64), oi2 = __shfl_xor(i2a, off, 64), oi3 = __shfl_xor(i3a, off, 64);
        INS3(b1a, b2a, b3a, i1a, i2a, i3a, ob1, oi1);
        INS3(b1a, b2a, b3a, i1a, i2a, i3a, ob2, oi2);
        INS3(b1a, b2a, b3a, i1a, i2a, i3a, ob3, oi3);
        ob1 = __shfl_xor(b1b, off, 64); ob2 = __shfl_xor(b2b, off, 64); ob3 = __shfl_xor(b3b, off, 64);
        oi1 = __shfl_xor(i1b, off, 64); oi2 = __shfl_xor(i2b, off, 64); oi3 = __shfl_xor(i3b, off, 64);
        INS3(b1b, b2b, b3b, i1b, i2b, i3b, ob1, oi1);
        INS3(b1b, b2b, b3b, i1b, i2b, i3b, ob2, oi2);
        INS3(b1b, b2b, b3b, i1b, i2b, i3b, ob3, oi3);
    }
    if (l < 16) {
        uint32_t f2 = (b2a - b1a < MARGIN) ? 1u : 0u;
        uint32_t f3 = (b3a - b1a < MARGIN) ? 1u : 0u;
        cand[m0w + l15] = (uint32_t)i1a | ((uint32_t)i2a << 10) | ((uint32_t)i3a << 20) | (f2 << 30) | (f3 << 31);
        f2 = (b2b - b1b < MARGIN) ? 1u : 0u;
        f3 = (b3b - b1b < MARGIN) ? 1u : 0u;
        cand[m0w + 16 + l15] = (uint32_t)i1b | ((uint32_t)i2b << 10) | ((uint32_t)i3b << 20) | (f2 << 30) | (f3 << 31);
    }
}

// Exact fp32 rescore of flagged rows (up to 3 candidates); writes final idx.
__global__ __launch_bounds__(256) void k_rescore(
    const float* __restrict__ x, const float* __restrict__ cb,
    const float* __restrict__ cnorm, const uint32_t* __restrict__ cand,
    int* __restrict__ idx_final) {
    __shared__ float pd[3][4][64];
    const int tid = threadIdx.x;
    const int b = blockIdx.x;
    const int n = b >> 5, t0 = (b & 31) * 64;
    const int tl = tid & 63, kq = tid >> 6;
    const int row = n * T_DIM + t0 + tl;
    const uint32_t wv = cand[row];
    const int j1 = (int)(wv & 1023u), j2 = (int)((wv >> 10) & 1023u), j3 = (int)((wv >> 20) & 1023u);
    const bool nd2 = (wv >> 30) & 1u, nd3 = (wv >> 31) & 1u;
    float d1 = 0.f, d2 = 0.f, d3 = 0.f;
    if (nd2) {
        const float* xc = x + (size_t)n * WIDTH * T_DIM + t0 + tl;
        const float* c1 = cb + (size_t)j1 * WIDTH;
        const float* c2 = cb + (size_t)j2 * WIDTH;
        const float* c3 = cb + (size_t)j3 * WIDTH;
#pragma unroll 4
        for (int k = kq * 128; k < kq * 128 + 128; ++k) {
            const float v = xc[(size_t)k * T_DIM];
            d1 = fmaf(v, c1[k], d1);
            d2 = fmaf(v, c2[k], d2);
            if (nd3) d3 = fmaf(v, c3[k], d3);
        }
    }
    pd[0][kq][tl] = d1; pd[1][kq][tl] = d2; pd[2][kq][tl] = d3;
    __syncthreads();
    if (tid < 64) {
        const uint32_t wv2 = cand[n * T_DIM + t0 + tid];
        const int k1 = (int)(wv2 & 1023u), k2 = (int)((wv2 >> 10) & 1023u), k3 = (int)((wv2 >> 20) & 1023u);
        const bool m2 = (wv2 >> 30) & 1u, m3 = (wv2 >> 31) & 1u;
        int win = k1;
        if (m2) {
            float qw = cnorm[k1] - 2.f * (pd[0][0][tid] + pd[0][1][tid] + pd[0][2][tid] + pd[0][3][tid]);
            const float q2 = cnorm[k2] - 2.f * (pd[1][0][tid] + pd[1][1][tid] + pd[1][2][tid] + pd[1][3][tid]);
            if (q2 < qw || (q2 == qw && k2 < win)) { win = k2; qw = q2; }
            if (m3) {
                const float q3 = cnorm[k3] - 2.f * (pd[2][0][tid] + pd[2][1][tid] + pd[2][2][tid] + pd[2][3][tid]);
                if (q3 < qw || (q3 == qw && k3 < win)) { win = k3; qw = q3; }
            }
        }
        idx_final[n * T_DIM + t0 + tid] = win;
    }
}

// Gather codebook[idx] -> out [N][W][T] via LDS transpose staging,
// idx as float, loss partials, histogram.
__global__ __launch_bounds__(256) void k_scatter(
    const float* __restrict__ x, const float* __restrict__ cb,
    const int* __restrict__ idx, float* __restrict__ dout,
    float* __restrict__ lossPart, int* __restrict__ hist) {
    __shared__ int sidx[64];
    __shared__ float tile[64][130];
    __shared__ float swsum[4];
    const int tid = threadIdx.x;
    const int b = blockIdx.x;
    const int n = b >> 5;
    const int t0 = (b & 31) * 64;
    if (tid < 64) {
        const int m = n * T_DIM + t0 + tid;
        const int ii = idx[m];
        sidx[tid] = ii;
        dout[IDX_OFF + m] = (float)ii;
        atomicAdd(&hist[ii], 1);
    }
    __syncthreads();
    const int w = tid >> 6, l = tid & 63;
    float ls = 0.f;
    for (int wc = 0; wc < 4; ++wc) {
#pragma unroll
        for (int rr = 0; rr < 16; ++rr) {
            const int row = w * 16 + rr;
            const float2 v = *(const float2*)(cb + (size_t)sidx[row] * WIDTH + wc * 128 + l * 2);
            *(float2*)&tile[row][l * 2] = v;
        }
        __syncthreads();
#pragma unroll 8
        for (int wwi = 0; wwi < 32; ++wwi) {
            const int ww = wc * 128 + w * 32 + wwi;
            const float val = tile[l][w * 32 + wwi];
            const size_t o = ((size_t)n * WIDTH + ww) * T_DIM + t0 + l;
            dout[o] = val;
            const float d = x[o] - val;
            ls = fmaf(d, d, ls);
        }
        __syncthreads();
    }
#pragma unroll
    for (int off = 32; off >= 1; off >>= 1) ls += __shfl_xor(ls, off, 64);
    if ((tid & 63) == 0) swsum[tid >> 6] = ls;
    __syncthreads();
    if (tid == 0) lossPart[b] = swsum[0] + swsum[1] + swsum[2] + swsum[3];
}

__global__ __launch_bounds__(256) void k_finalize(
    const int* __restrict__ hist, const float* __restrict__ lossPart,
    float* __restrict__ dout) {
    const int tid = threadIdx.x;
    float e = 0.f, ls = 0.f;
    for (int c = tid; c < NB_CODE; c += 256) {
        const float p = (float)hist[c] * (1.0f / (float)M_ROWS);
        e += p * logf(p + 1e-7f);
        ls += lossPart[c];
    }
#pragma unroll
    for (int off = 32; off >= 1; off >>= 1) {
        e += __shfl_xor(e, off, 64);
        ls += __shfl_xor(ls, off, 64);
    }
    __shared__ float se[4], sl[4];
    if ((tid & 63) == 0) { se[tid >> 6] = e; sl[tid >> 6] = ls; }
    __syncthreads();
    if (tid == 0) {
        const float E = se[0] + se[1] + se[2] + se[3];
        const float L = sl[0] + sl[1] + sl[2] + sl[3];
        dout[LOSS_OFF] = L / (float)OUT_ELEMS;
        dout[PERP_OFF] = expf(-E);
    }
}

extern "C" void kernel_launch(void* const* d_in, const int* in_sizes, int n_in,
                              void* d_out, int out_size, void* d_ws, size_t ws_size,
                              hipStream_t stream) {
    const float* x = (const float*)d_in[0];
    const float* cb = (const float*)d_in[1];
    float* dout = (float*)d_out;
    uint8_t* w = (uint8_t*)d_ws;

    unsigned short* cbh = (unsigned short*)w;                       // 1 MB
    float* cnorm = (float*)(w + (1u << 20));                        // 4 KB
    uint32_t* cand = (uint32_t*)(w + (1u << 20) + 4096);            // 256 KB
    int* idx_final = (int*)(w + (1u << 20) + (1u << 19));           // 256 KB @1.5MB
    int* hist = (int*)(w + (2u << 20));                             // 4 KB
    float* lossPart = (float*)(w + (2u << 20) + 4096);              // 4 KB
    unsigned short* xT = (unsigned short*)d_out;                    // 67 MB scratch in out buf

    k_prep<<<NB_CODE, 128, 0, stream>>>(cb, cbh, cnorm, hist);
    k_xprep<<<dim3(T_DIM / 32, WIDTH / 32, N_BATCH), dim3(32, 8), 0, stream>>>(x, xT);
    k_argmin<<<M_ROWS / 128, 256, 0, stream>>>(xT, cbh, cnorm, cand);
    k_rescore<<<1024, 256, 0, stream>>>(x, cb, cnorm, cand, idx_final);
    k_scatter<<<1024, 256, 0, stream>>>(x, cb, idx_final, dout, lossPart, hist);
    k_finalize<<<1, 256, 0, stream>>>(hist, lossPart, dout);
}

// Round 7
// 304.681 us; speedup vs baseline: 1.0402x; 1.0402x over previous
//
#include <hip/hip_runtime.h>
#include <cstddef>
#include <cstdint>

#define N_BATCH 32
#define WIDTH   512
#define T_DIM   2048
#define NB_CODE 1024
#define M_ROWS  65536
#define OUT_ELEMS 33554432
#define IDX_OFF  OUT_ELEMS
#define LOSS_OFF (OUT_ELEMS + M_ROWS)
#define PERP_OFF (LOSS_OFF + 1)
#define MARGIN   0.75f

typedef __attribute__((ext_vector_type(8))) short vshort8;
typedef __attribute__((ext_vector_type(4))) float vfloat4;

typedef __attribute__((address_space(1))) const uint32_t gu32_t;
typedef __attribute__((address_space(3))) uint32_t lu32_t;
static __device__ __forceinline__ void gload16(const void* g, void* l) {
    __builtin_amdgcn_global_load_lds((gu32_t*)g, (lu32_t*)l, 16, 0, 0);
}

static __device__ __forceinline__ unsigned short f2bf(float f) {
    uint32_t u = __float_as_uint(f);
    uint32_t r = (u + 0x7FFFu + ((u >> 16) & 1u)) >> 16;  // RNE
    return (unsigned short)r;
}
static __device__ __forceinline__ float bf2f(unsigned short s) {
    return __uint_as_float(((uint32_t)s) << 16);
}
static __device__ __forceinline__ vshort8 ntload8(const unsigned short* p) {
    return __builtin_nontemporal_load((const vshort8*)p);
}

// ---------------- workspace layout (bytes) ----------------
// cbh 1MB | cnorm 4K | hist 4K | cand 256K | idx 256K | sbest 256K | xnorm 256K
// xTh (bf16 [65536][512]) at d_out[0..64MiB) -- scratch, overwritten by k_scatter.

// bf16 codebook + per-code norms + hist zeroing.
__global__ __launch_bounds__(128) void k_prep(const float* __restrict__ cb,
                                              unsigned short* __restrict__ cbh,
                                              float* __restrict__ cnorm,
                                              int* __restrict__ hist) {
    const int c = blockIdx.x, tid = threadIdx.x;
    float4 v = ((const float4*)(cb + (size_t)c * WIDTH))[tid];
    ushort4 h;
    h.x = f2bf(v.x); h.y = f2bf(v.y); h.z = f2bf(v.z); h.w = f2bf(v.w);
    ((ushort4*)(cbh + (size_t)c * WIDTH))[tid] = h;
    float s = v.x * v.x + v.y * v.y + v.z * v.z + v.w * v.w;
#pragma unroll
    for (int off = 32; off >= 1; off >>= 1) s += __shfl_xor(s, off, 64);
    __shared__ float sw[2];
    if ((tid & 63) == 0) sw[tid >> 6] = s;
    __syncthreads();
    if (tid == 0) { cnorm[c] = sw[0] + sw[1]; hist[c] = 0; }
}

// x [n][k][t] f32 -> xTh [n*T+t][k] bf16 + exact fp32 row norms.
__global__ __launch_bounds__(256) void k_xprep(const float* __restrict__ x,
                                               unsigned short* __restrict__ xTh,
                                               float* __restrict__ xnorm) {
    __shared__ float tile[128][36];
    __shared__ float xns[8][32];
    const int tid = threadIdx.x;
    const int t0 = blockIdx.x * 32;
    const int n = blockIdx.y;
    const int m0 = n * T_DIM + t0;
    const int r = tid & 31, kg = tid >> 5;   // row (t) / k-group
    const int kl = tid >> 3, t4 = tid & 7;   // load mapping
    float xn = 0.f;
    for (int c = 0; c < 4; ++c) {            // 4 chunks of 128 k
#pragma unroll
        for (int s = 0; s < 4; ++s) {
            const int k = s * 32 + kl;
            float4 v = *(const float4*)(x + (size_t)(n * WIDTH + c * 128 + k) * T_DIM + t0 + t4 * 4);
            *(float4*)&tile[k][t4 * 4] = v;
        }
        __syncthreads();
        vshort8 h0, h1;
#pragma unroll
        for (int e = 0; e < 16; ++e) {
            const float v = tile[kg * 16 + e][r];
            const unsigned short h = f2bf(v);
            if (e < 8) h0[e] = (short)h;
            else       h1[e - 8] = (short)h;
            xn = fmaf(v, v, xn);
        }
        unsigned short* ph = xTh + (size_t)(m0 + r) * WIDTH + c * 128 + kg * 16;
        *(vshort8*)ph = h0; *(vshort8*)(ph + 8) = h1;
        __syncthreads();
    }
    xns[kg][r] = xn;
    __syncthreads();
    if (tid < 32) {
        float s = 0.f;
#pragma unroll
        for (int g = 0; g < 8; ++g) s += xns[g][tid];
        xnorm[m0 + tid] = s;
    }
}

// hh-screen argmin: 256 thr = 4 waves, 64 rows/block (16 rows/wave).
// 2x16KB LDS dbuf + cns = 36KB -> 4 blocks/CU (16 waves). Depth-1 prefetch,
// two COUNTED barriers per phase (vmcnt(4), no full drain until tail).
__global__ __launch_bounds__(256, 4) void k_argmin(
    const unsigned short* __restrict__ xT, const unsigned short* __restrict__ cbh,
    const float* __restrict__ cnorm, uint32_t* __restrict__ cand,
    float* __restrict__ sbest) {
    __shared__ __align__(16) short lds[2][8192];   // 2 x 16KB
    __shared__ __align__(16) float cns[NB_CODE];

    const int tid = threadIdx.x;
    const int w = tid >> 6, l = tid & 63;
    const int l15 = l & 15, lg = l >> 4;
    const int rowl = l >> 3;
    const int srccol = ((l & 7) * 16) ^ (rowl << 4);

#define STAGE(T) do {                                                               \
    const int cc_ = (T) >> 3, kc_ = (T) & 7;                                        \
    const char* gb_ = ((const char*)cbh) +                                          \
        (((size_t)(cc_ * 128 + w * 32 + rowl)) << 10) + kc_ * 128 + srccol;         \
    short* lb_ = &lds[(T) & 1][w * 2048];                                           \
    gload16(gb_,         lb_);                                                      \
    gload16(gb_ + 8192,  lb_ + 512);                                                \
    gload16(gb_ + 16384, lb_ + 1024);                                               \
    gload16(gb_ + 24576, lb_ + 1536);                                               \
} while (0)

    STAGE(0);
    { float4 c4 = ((const float4*)cnorm)[tid]; *(float4*)&cns[tid * 4] = c4; }

    // x fragments: 16 rows/wave, full K=512, nontemporal (read-once stream).
    const int m0w = blockIdx.x * 64 + w * 16;
    const unsigned short* xb = xT + (size_t)(m0w + l15) * WIDTH;
    vshort8 xh[16];
#pragma unroll
    for (int ks = 0; ks < 16; ++ks) xh[ks] = ntload8(xb + ks * 32 + lg * 8);

    const int mask = (l15 & 7) << 3;
    const int rd0 = l15 * 64 + ((lg * 8) ^ mask);
    const int rd1 = rd0 ^ 32;

    float b1 = 3.4e38f, b2 = 3.4e38f, b3 = 3.4e38f;
    int i1 = 0, i2 = 0, i3 = 0;

#define INS3(S, C) do {                                                       \
        const bool lt1 = (S) < b1, lt2 = (S) < b2, lt3 = (S) < b3;            \
        b3 = lt3 ? (lt2 ? b2 : (S)) : b3;  i3 = lt3 ? (lt2 ? i2 : (C)) : i3; \
        b2 = lt2 ? (lt1 ? b1 : (S)) : b2;  i2 = lt2 ? (lt1 ? i1 : (C)) : i2; \
        b1 = lt1 ? (S) : b1;               i1 = lt1 ? (C) : i1;              \
    } while (0)

    __syncthreads();   // startup drain: tile0 + cns + x frags all complete

    for (int cc = 0; cc < 8; ++cc) {
        vfloat4 acc[8];
#pragma unroll
        for (int fm = 0; fm < 8; ++fm) { vfloat4 z = {0.f, 0.f, 0.f, 0.f}; acc[fm] = z; }

#pragma unroll
        for (int kc = 0; kc < 8; ++kc) {
            const int t = cc * 8 + kc;
            // bar_a: everyone done reading buf (t-1)&1 before we overwrite it
            __builtin_amdgcn_s_barrier();
            if (t < 63) {
                STAGE(t + 1);
                asm volatile("s_waitcnt vmcnt(4)" ::: "memory");  // stage t landed
            } else {
                asm volatile("s_waitcnt vmcnt(0)" ::: "memory");
            }
            __builtin_amdgcn_s_barrier();  // bar_b: all waves' stage t visible
            const short* lb = lds[t & 1];
            __builtin_amdgcn_s_setprio(1);
#pragma unroll
            for (int fm = 0; fm < 8; ++fm) {
                vshort8 a0 = *(const vshort8*)&lb[rd0 + fm * 1024];
                acc[fm] = __builtin_amdgcn_mfma_f32_16x16x32_bf16(a0, xh[kc * 2], acc[fm], 0, 0, 0);
            }
#pragma unroll
            for (int fm = 0; fm < 8; ++fm) {
                vshort8 a1 = *(const vshort8*)&lb[rd1 + fm * 1024];
                acc[fm] = __builtin_amdgcn_mfma_f32_16x16x32_bf16(a1, xh[kc * 2 + 1], acc[fm], 0, 0, 0);
            }
            __builtin_amdgcn_s_setprio(0);
            if (kc == 7) {
#pragma unroll
                for (int fm = 0; fm < 8; ++fm) {
                    const int cb0 = cc * 128 + fm * 16 + lg * 4;
                    vfloat4 cn = *(const vfloat4*)&cns[cb0];
#pragma unroll
                    for (int r = 0; r < 4; ++r) {
                        const float s = fmaf(-2.f, acc[fm][r], cn[r]);
                        INS3(s, cb0 + r);
                    }
                }
            }
        }
    }

    // merge top-3 across the 4 lg groups (lane bits 4,5)
#pragma unroll
    for (int off = 16; off <= 32; off <<= 1) {
        const float ob1 = __shfl_xor(b1, off, 64), ob2 = __shfl_xor(b2, off, 64), ob3 = __shfl_xor(b3, off, 64);
        const int oi1 = __shfl_xor(i1, off, 64), oi2 = __shfl_xor(i2, off, 64), oi3 = __shfl_xor(i3, off, 64);
        INS3(ob1, oi1); INS3(ob2, oi2); INS3(ob3, oi3);
    }
    if (l < 16) {
        const uint32_t f2 = (b2 - b1 < MARGIN) ? 1u : 0u;
        const uint32_t f3 = (b3 - b1 < MARGIN) ? 1u : 0u;
        cand[m0w + l] = (uint32_t)i1 | ((uint32_t)i2 << 10) | ((uint32_t)i3 << 20) | (f2 << 30) | (f3 << 31);
        sbest[m0w + l] = b1;   // screen-score of winner (overwritten if rescored)
    }
}

// EXACT fp32 rescore of flagged rows (original x + fp32 cb), one wave/row.
// Writes final idx + exact winning score.
__global__ __launch_bounds__(256) void k_rescore(
    const float* __restrict__ x, const float* __restrict__ cb,
    const float* __restrict__ cnorm, const uint32_t* __restrict__ cand,
    int* __restrict__ idx_final, float* __restrict__ sbest) {
    __shared__ int list[64];
    __shared__ int cnt;
    const int tid = threadIdx.x;
    const int m0 = blockIdx.x * 64;
    if (tid == 0) cnt = 0;
    __syncthreads();
    if (tid < 64) {
        const uint32_t wv = cand[m0 + tid];
        if (wv >> 30) { const int p = atomicAdd(&cnt, 1); list[p] = tid; }
        else idx_final[m0 + tid] = (int)(wv & 1023u);
    }
    __syncthreads();
    const int nf = cnt;
    const int w = tid >> 6, lid = tid & 63;
    for (int it = w; it < nf; it += 4) {
        const int row = m0 + list[it];
        const uint32_t wv = cand[row];
        const int j1 = (int)(wv & 1023u), j2 = (int)((wv >> 10) & 1023u), j3 = (int)((wv >> 20) & 1023u);
        const bool nd3 = (wv >> 31) & 1u;
        const int n = row >> 11, t = row & 2047;
        const float* xc = x + (size_t)n * WIDTH * T_DIM + t;
        float xv[8];
#pragma unroll
        for (int e = 0; e < 8; ++e)
            xv[e] = xc[(size_t)(lid * 8 + e) * T_DIM];
        float d1 = 0.f, d2 = 0.f, d3 = 0.f;
        {
            const float* c1 = cb + (size_t)j1 * WIDTH + lid * 8;
            const float* c2 = cb + (size_t)j2 * WIDTH + lid * 8;
            const float* c3 = cb + (size_t)j3 * WIDTH + lid * 8;
            float4 a0 = *(const float4*)c1, a1 = *(const float4*)(c1 + 4);
            d1 = fmaf(xv[0], a0.x, fmaf(xv[1], a0.y, fmaf(xv[2], a0.z, fmaf(xv[3], a0.w,
                 fmaf(xv[4], a1.x, fmaf(xv[5], a1.y, fmaf(xv[6], a1.z, xv[7] * a1.w)))))));
            float4 b0 = *(const float4*)c2, b1v = *(const float4*)(c2 + 4);
            d2 = fmaf(xv[0], b0.x, fmaf(xv[1], b0.y, fmaf(xv[2], b0.z, fmaf(xv[3], b0.w,
                 fmaf(xv[4], b1v.x, fmaf(xv[5], b1v.y, fmaf(xv[6], b1v.z, xv[7] * b1v.w)))))));
            if (nd3) {
                float4 g0 = *(const float4*)c3, g1 = *(const float4*)(c3 + 4);
                d3 = fmaf(xv[0], g0.x, fmaf(xv[1], g0.y, fmaf(xv[2], g0.z, fmaf(xv[3], g0.w,
                     fmaf(xv[4], g1.x, fmaf(xv[5], g1.y, fmaf(xv[6], g1.z, xv[7] * g1.w)))))));
            }
        }
#pragma unroll
        for (int off = 32; off >= 1; off >>= 1) {
            d1 += __shfl_xor(d1, off, 64);
            d2 += __shfl_xor(d2, off, 64);
            d3 += __shfl_xor(d3, off, 64);
        }
        if (lid == 0) {
            int win = j1;
            float qw = fmaf(-2.f, d1, cnorm[j1]);
            const float q2 = fmaf(-2.f, d2, cnorm[j2]);
            if (q2 < qw || (q2 == qw && j2 < win)) { win = j2; qw = q2; }
            if (nd3) {
                const float q3 = fmaf(-2.f, d3, cnorm[j3]);
                if (q3 < qw || (q3 == qw && j3 < win)) { win = j3; qw = q3; }
            }
            idx_final[row] = win;
            sbest[row] = qw;
        }
    }
}

// Gather codebook[idx] -> out [N][W][T] via LDS transpose staging,
// idx as float, histogram. (No x reads -- loss comes from the dist identity.)
__global__ __launch_bounds__(256) void k_scatter(
    const float* __restrict__ cb, const int* __restrict__ idx,
    float* __restrict__ dout, int* __restrict__ hist) {
    __shared__ int sidx[64];
    __shared__ float tile[64][130];
    const int tid = threadIdx.x;
    const int b = blockIdx.x;
    const int n = b >> 5;
    const int t0 = (b & 31) * 64;
    if (tid < 64) {
        const int m = n * T_DIM + t0 + tid;
        const int ii = idx[m];
        sidx[tid] = ii;
        dout[IDX_OFF + m] = (float)ii;
        atomicAdd(&hist[ii], 1);
    }
    __syncthreads();
    const int w = tid >> 6, l = tid & 63;
    for (int wc = 0; wc < 4; ++wc) {
#pragma unroll
        for (int rr = 0; rr < 16; ++rr) {
            const int row = w * 16 + rr;
            const float2 v = *(const float2*)(cb + (size_t)sidx[row] * WIDTH + wc * 128 + l * 2);
            *(float2*)&tile[row][l * 2] = v;
        }
        __syncthreads();
#pragma unroll 8
        for (int wwi = 0; wwi < 32; ++wwi) {
            const int ww = wc * 128 + w * 32 + wwi;
            dout[((size_t)n * WIDTH + ww) * T_DIM + t0 + l] = tile[l][w * 32 + wwi];
        }
        __syncthreads();
    }
}

// perplexity from hist + commit loss = sum(xnorm + s_win) / OUT_ELEMS
__global__ __launch_bounds__(1024) void k_finalize(
    const int* __restrict__ hist, const float* __restrict__ xnorm,
    const float* __restrict__ sbest, float* __restrict__ dout) {
    const int tid = threadIdx.x;
    float e;
    {
        const float p = (float)hist[tid] * (1.0f / (float)M_ROWS);
        e = p * logf(p + 1e-7f);
    }
    float ls = 0.f;
    for (int i = tid; i < M_ROWS; i += 1024) ls += xnorm[i] + sbest[i];
#pragma unroll
    for (int off = 32; off >= 1; off >>= 1) {
        e += __shfl_xor(e, off, 64);
        ls += __shfl_xor(ls, off, 64);
    }
    __shared__ float se[16], sl[16];
    if ((tid & 63) == 0) { se[tid >> 6] = e; sl[tid >> 6] = ls; }
    __syncthreads();
    if (tid == 0) {
        float E = 0.f, L = 0.f;
#pragma unroll
        for (int i = 0; i < 16; ++i) { E += se[i]; L += sl[i]; }
        dout[LOSS_OFF] = L / (float)OUT_ELEMS;
        dout[PERP_OFF] = expf(-E);
    }
}

extern "C" void kernel_launch(void* const* d_in, const int* in_sizes, int n_in,
                              void* d_out, int out_size, void* d_ws, size_t ws_size,
                              hipStream_t stream) {
    const float* x = (const float*)d_in[0];
    const float* cb = (const float*)d_in[1];
    float* dout = (float*)d_out;
    uint8_t* w = (uint8_t*)d_ws;

    unsigned short* cbh = (unsigned short*)w;                        // 1 MB
    float* cnorm   = (float*)(w + (1u << 20));                       // 4 KB
    int*   hist    = (int*)(w + (1u << 20) + 4096);                  // 4 KB
    uint32_t* cand = (uint32_t*)(w + (1u << 20) + 8192);             // 256 KB
    int* idx_final = (int*)(w + (1u << 20) + 8192 + 262144);         // 256 KB
    float* sbest   = (float*)(w + (1u << 20) + 8192 + 2 * 262144);   // 256 KB
    float* xnorm   = (float*)(w + (1u << 20) + 8192 + 3 * 262144);   // 256 KB

    unsigned short* xTh = (unsigned short*)d_out;                    // 64 MiB scratch

    k_prep<<<NB_CODE, 128, 0, stream>>>(cb, cbh, cnorm, hist);
    k_xprep<<<dim3(T_DIM / 32, N_BATCH), 256, 0, stream>>>(x, xTh, xnorm);
    k_argmin<<<M_ROWS / 64, 256, 0, stream>>>(xTh, cbh, cnorm, cand, sbest);
    k_rescore<<<1024, 256, 0, stream>>>(x, cb, cnorm, cand, idx_final, sbest);
    k_scatter<<<1024, 256, 0, stream>>>(cb, idx_final, dout, hist);
    k_finalize<<<1, 1024, 0, stream>>>(hist, xnorm, sbest, dout);
}

// Round 8
// 222.345 us; speedup vs baseline: 1.4254x; 1.3703x over previous
//
#include <hip/hip_runtime.h>
#include <cstddef>
#include <cstdint>

#define N_BATCH 32
#define WIDTH   512
#define T_DIM   2048
#define NB_CODE 1024
#define M_ROWS  65536
#define OUT_ELEMS 33554432
#define IDX_OFF  OUT_ELEMS
#define LOSS_OFF (OUT_ELEMS + M_ROWS)
#define PERP_OFF (LOSS_OFF + 1)
#define MARGIN   0.75f

typedef __attribute__((ext_vector_type(8))) short vshort8;
typedef __attribute__((ext_vector_type(4))) float vfloat4;
typedef __attribute__((ext_vector_type(16))) float vfloat16;

typedef __attribute__((address_space(1))) const uint32_t gu32_t;
typedef __attribute__((address_space(3))) uint32_t lu32_t;
static __device__ __forceinline__ void gload16(const void* g, void* l) {
    __builtin_amdgcn_global_load_lds((gu32_t*)g, (lu32_t*)l, 16, 0, 0);
}

static __device__ __forceinline__ unsigned short f2bf(float f) {
    uint32_t u = __float_as_uint(f);
    uint32_t r = (u + 0x7FFFu + ((u >> 16) & 1u)) >> 16;  // RNE
    return (unsigned short)r;
}
static __device__ __forceinline__ float bf2f(unsigned short s) {
    return __uint_as_float(((uint32_t)s) << 16);
}
static __device__ __forceinline__ vshort8 ntload8(const unsigned short* p) {
    return __builtin_nontemporal_load((const vshort8*)p);
}

// ---------------- workspace layout (bytes) ----------------
// cbh 1MB | cnorm 4K | hist 4K | cand 256K | idx 256K | sbest 256K | xnorm 256K
// xTh (bf16 [65536][512]) at d_out[0..64MiB) -- scratch, overwritten by k_scatter.

// bf16 codebook + per-code norms + hist zeroing.
__global__ __launch_bounds__(128) void k_prep(const float* __restrict__ cb,
                                              unsigned short* __restrict__ cbh,
                                              float* __restrict__ cnorm,
                                              int* __restrict__ hist) {
    const int c = blockIdx.x, tid = threadIdx.x;
    float4 v = ((const float4*)(cb + (size_t)c * WIDTH))[tid];
    ushort4 h;
    h.x = f2bf(v.x); h.y = f2bf(v.y); h.z = f2bf(v.z); h.w = f2bf(v.w);
    ((ushort4*)(cbh + (size_t)c * WIDTH))[tid] = h;
    float s = v.x * v.x + v.y * v.y + v.z * v.z + v.w * v.w;
#pragma unroll
    for (int off = 32; off >= 1; off >>= 1) s += __shfl_xor(s, off, 64);
    __shared__ float sw[2];
    if ((tid & 63) == 0) sw[tid >> 6] = s;
    __syncthreads();
    if (tid == 0) { cnorm[c] = sw[0] + sw[1]; hist[c] = 0; }
}

// x [n][k][t] f32 -> xTh [n*T+t][k] bf16 + exact fp32 row norms.
__global__ __launch_bounds__(256) void k_xprep(const float* __restrict__ x,
                                               unsigned short* __restrict__ xTh,
                                               float* __restrict__ xnorm) {
    __shared__ float tile[128][36];
    __shared__ float xns[8][32];
    const int tid = threadIdx.x;
    const int t0 = blockIdx.x * 32;
    const int n = blockIdx.y;
    const int m0 = n * T_DIM + t0;
    const int r = tid & 31, kg = tid >> 5;   // row (t) / k-group
    const int kl = tid >> 3, t4 = tid & 7;   // load mapping
    float xn = 0.f;
    for (int c = 0; c < 4; ++c) {            // 4 chunks of 128 k
#pragma unroll
        for (int s = 0; s < 4; ++s) {
            const int k = s * 32 + kl;
            float4 v = *(const float4*)(x + (size_t)(n * WIDTH + c * 128 + k) * T_DIM + t0 + t4 * 4);
            *(float4*)&tile[k][t4 * 4] = v;
        }
        __syncthreads();
        vshort8 h0, h1;
#pragma unroll
        for (int e = 0; e < 16; ++e) {
            const float v = tile[kg * 16 + e][r];
            const unsigned short h = f2bf(v);
            if (e < 8) h0[e] = (short)h;
            else       h1[e - 8] = (short)h;
            xn = fmaf(v, v, xn);
        }
        unsigned short* ph = xTh + (size_t)(m0 + r) * WIDTH + c * 128 + kg * 16;
        *(vshort8*)ph = h0; *(vshort8*)(ph + 8) = h1;
        __syncthreads();
    }
    xns[kg][r] = xn;
    __syncthreads();
    if (tid < 32) {
        float s = 0.f;
#pragma unroll
        for (int g = 0; g < 8; ++g) s += xns[g][tid];
        xnorm[m0 + tid] = s;
    }
}

// hh-screen argmin, 32x32x16 MFMA. 512 thr = 8 waves, 256 rows/block,
// 32 rows/wave (x full-K in regs). Codebook streamed in 16 chunks of
// 64 codes x 512 k (64KB), double-buffered; ONE barrier + ONE vmcnt(0)
// per chunk (stage has a full compute phase of cover). LDS layout
// [kb][code][128 bf16] with ^((code&15)<<4) swizzle -> 2-way (free).
__global__ __launch_bounds__(512, 2) void k_argmin(
    const unsigned short* __restrict__ xT, const unsigned short* __restrict__ cbh,
    const float* __restrict__ cnorm, uint32_t* __restrict__ cand,
    float* __restrict__ sbest) {
    __shared__ __align__(16) short lds[2][32768];   // 2 x 64KB
    __shared__ __align__(16) float cns[NB_CODE];

    const int tid = threadIdx.x;
    const int wv = tid >> 6, l = tid & 63;
    const int l31 = l & 31, hi = l >> 5;
    const int m = l31 & 15;

    // staging source offsets (inverse swizzle), lds linear slot q = wv*512+j*64+l
    int srcoff[8];
#pragma unroll
    for (int j = 0; j < 8; ++j) {
        const int q = wv * 512 + j * 64 + l;
        const int kb = q >> 10, code = (q >> 4) & 63, s = q & 15;
        srcoff[j] = code * 1024 + kb * 256 + ((s ^ (code & 15)) << 4);
    }

#define STAGE(SP, B) do {                                                     \
    const char* cbbase_ = ((const char*)cbh) + (SP) * 65536;                  \
    short* lb_ = &lds[B][0];                                                  \
    _Pragma("unroll")                                                         \
    for (int j = 0; j < 8; ++j)                                               \
        gload16(cbbase_ + srcoff[j], lb_ + (wv * 512 + j * 64) * 8);          \
} while (0)

    STAGE(0, 0);

    { ((float2*)cns)[tid] = ((const float2*)cnorm)[tid]; }

    // x fragments: 32 rows/wave, full K=512. lane holds row l31, k-half hi.
    const int m0w = blockIdx.x * 256 + wv * 32;
    const unsigned short* xb = xT + (size_t)(m0w + l31) * WIDTH + hi * 8;
    vshort8 xh[32];
#pragma unroll
    for (int ks = 0; ks < 32; ++ks) xh[ks] = ntload8(xb + ks * 16);

    // swizzled ds_read base (shorts): row=tl*32+l31 (256B rows), slot XOR
    const int B34 = (m >> 1) << 4;                 // XOR mask on slot bits (shorts<<4)
    const int base_s = l31 * 128 + ((hi ^ (m & 1)) << 3);

    float b1 = 3.4e38f, b2 = 3.4e38f, b3 = 3.4e38f;
    int i1 = 0, i2 = 0, i3 = 0;

#define INS3(S, C) do {                                                       \
        const bool lt1 = (S) < b1, lt2 = (S) < b2, lt3 = (S) < b3;            \
        b3 = lt3 ? (lt2 ? b2 : (S)) : b3;  i3 = lt3 ? (lt2 ? i2 : (C)) : i3; \
        b2 = lt2 ? (lt1 ? b1 : (S)) : b2;  i2 = lt2 ? (lt1 ? i1 : (C)) : i2; \
        b1 = lt1 ? (S) : b1;               i1 = lt1 ? (C) : i1;              \
    } while (0)

    __syncthreads();   // full drain: chunk0, cns, x frags

    for (int sp = 0; sp < 16; ++sp) {
        if (sp) {
            asm volatile("s_waitcnt vmcnt(0)" ::: "memory");  // own STAGE(sp) done
            __builtin_amdgcn_s_barrier();                     // everyone's done
        }
        if (sp < 15) {
            if (sp & 1) STAGE(sp + 1, 0); else STAGE(sp + 1, 1);
        }
        const short* buf = lds[sp & 1];
        vfloat16 acc0 = {}, acc1 = {};
        __builtin_amdgcn_s_setprio(1);
#pragma unroll
        for (int ks = 0; ks < 32; ++ks) {
            const int koff = ((ks >> 3) << 13) + (((ks & 7) << 4) ^ B34);
            vshort8 a0 = *(const vshort8*)&buf[base_s + koff];
            acc0 = __builtin_amdgcn_mfma_f32_32x32x16_bf16(a0, xh[ks], acc0, 0, 0, 0);
            vshort8 a1 = *(const vshort8*)&buf[base_s + koff + 4096];
            acc1 = __builtin_amdgcn_mfma_f32_32x32x16_bf16(a1, xh[ks], acc1, 0, 0, 0);
        }
        __builtin_amdgcn_s_setprio(0);
        // score 64 codes: D[code][xrow], col=lane&31=row, code=(r&3)+8*(r>>2)+4*hi
        const int cb0 = sp * 64;
#pragma unroll
        for (int tl = 0; tl < 2; ++tl) {
#pragma unroll
            for (int g = 0; g < 4; ++g) {
                const int cbase = cb0 + tl * 32 + g * 8 + 4 * hi;
                vfloat4 cn = *(const vfloat4*)&cns[cbase];
#pragma unroll
                for (int j = 0; j < 4; ++j) {
                    const float a = tl ? acc1[g * 4 + j] : acc0[g * 4 + j];
                    const float s = fmaf(-2.f, a, cn[j]);
                    INS3(s, cbase + j);
                }
            }
        }
    }

    // merge top-3 across the hi halves (disjoint code sets)
    {
        const float ob1 = __shfl_xor(b1, 32, 64), ob2 = __shfl_xor(b2, 32, 64), ob3 = __shfl_xor(b3, 32, 64);
        const int oi1 = __shfl_xor(i1, 32, 64), oi2 = __shfl_xor(i2, 32, 64), oi3 = __shfl_xor(i3, 32, 64);
        INS3(ob1, oi1); INS3(ob2, oi2); INS3(ob3, oi3);
    }
    if (l < 32) {
        const uint32_t f2 = (b2 - b1 < MARGIN) ? 1u : 0u;
        const uint32_t f3 = (b3 - b1 < MARGIN) ? 1u : 0u;
        cand[m0w + l] = (uint32_t)i1 | ((uint32_t)i2 << 10) | ((uint32_t)i3 << 20) | (f2 << 30) | (f3 << 31);
        sbest[m0w + l] = b1;   // screen-score of winner (overwritten if rescored)
    }
}

// EXACT fp32 rescore of flagged rows (original x + fp32 cb), one wave/row.
// Writes final idx + exact winning score.
__global__ __launch_bounds__(256) void k_rescore(
    const float* __restrict__ x, const float* __restrict__ cb,
    const float* __restrict__ cnorm, const uint32_t* __restrict__ cand,
    int* __restrict__ idx_final, float* __restrict__ sbest) {
    __shared__ int list[64];
    __shared__ int cnt;
    const int tid = threadIdx.x;
    const int m0 = blockIdx.x * 64;
    if (tid == 0) cnt = 0;
    __syncthreads();
    if (tid < 64) {
        const uint32_t wv = cand[m0 + tid];
        if (wv >> 30) { const int p = atomicAdd(&cnt, 1); list[p] = tid; }
        else idx_final[m0 + tid] = (int)(wv & 1023u);
    }
    __syncthreads();
    const int nf = cnt;
    const int w = tid >> 6, lid = tid & 63;
    for (int it = w; it < nf; it += 4) {
        const int row = m0 + list[it];
        const uint32_t wv = cand[row];
        const int j1 = (int)(wv & 1023u), j2 = (int)((wv >> 10) & 1023u), j3 = (int)((wv >> 20) & 1023u);
        const bool nd3 = (wv >> 31) & 1u;
        const int n = row >> 11, t = row & 2047;
        const float* xc = x + (size_t)n * WIDTH * T_DIM + t;
        float xv[8];
#pragma unroll
        for (int e = 0; e < 8; ++e)
            xv[e] = xc[(size_t)(lid * 8 + e) * T_DIM];
        float d1 = 0.f, d2 = 0.f, d3 = 0.f;
        {
            const float* c1 = cb + (size_t)j1 * WIDTH + lid * 8;
            const float* c2 = cb + (size_t)j2 * WIDTH + lid * 8;
            const float* c3 = cb + (size_t)j3 * WIDTH + lid * 8;
            float4 a0 = *(const float4*)c1, a1 = *(const float4*)(c1 + 4);
            d1 = fmaf(xv[0], a0.x, fmaf(xv[1], a0.y, fmaf(xv[2], a0.z, fmaf(xv[3], a0.w,
                 fmaf(xv[4], a1.x, fmaf(xv[5], a1.y, fmaf(xv[6], a1.z, xv[7] * a1.w)))))));
            float4 b0 = *(const float4*)c2, b1v = *(const float4*)(c2 + 4);
            d2 = fmaf(xv[0], b0.x, fmaf(xv[1], b0.y, fmaf(xv[2], b0.z, fmaf(xv[3], b0.w,
                 fmaf(xv[4], b1v.x, fmaf(xv[5], b1v.y, fmaf(xv[6], b1v.z, xv[7] * b1v.w)))))));
            if (nd3) {
                float4 g0 = *(const float4*)c3, g1 = *(const float4*)(c3 + 4);
                d3 = fmaf(xv[0], g0.x, fmaf(xv[1], g0.y, fmaf(xv[2], g0.z, fmaf(xv[3], g0.w,
                     fmaf(xv[4], g1.x, fmaf(xv[5], g1.y, fmaf(xv[6], g1.z, xv[7] * g1.w)))))));
            }
        }
#pragma unroll
        for (int off = 32; off >= 1; off >>= 1) {
            d1 += __shfl_xor(d1, off, 64);
            d2 += __shfl_xor(d2, off, 64);
            d3 += __shfl_xor(d3, off, 64);
        }
        if (lid == 0) {
            int win = j1;
            float qw = fmaf(-2.f, d1, cnorm[j1]);
            const float q2 = fmaf(-2.f, d2, cnorm[j2]);
            if (q2 < qw || (q2 == qw && j2 < win)) { win = j2; qw = q2; }
            if (nd3) {
                const float q3 = fmaf(-2.f, d3, cnorm[j3]);
                if (q3 < qw || (q3 == qw && j3 < win)) { win = j3; qw = q3; }
            }
            idx_final[row] = win;
            sbest[row] = qw;
        }
    }
}

// Gather codebook[idx] -> out [N][W][T] via LDS transpose staging,
// idx as float, histogram. (No x reads -- loss comes from the dist identity.)
__global__ __launch_bounds__(256) void k_scatter(
    const float* __restrict__ cb, const int* __restrict__ idx,
    float* __restrict__ dout, int* __restrict__ hist) {
    __shared__ int sidx[64];
    __shared__ float tile[64][130];
    const int tid = threadIdx.x;
    const int b = blockIdx.x;
    const int n = b >> 5;
    const int t0 = (b & 31) * 64;
    if (tid < 64) {
        const int m2 = n * T_DIM + t0 + tid;
        const int ii = idx[m2];
        sidx[tid] = ii;
        dout[IDX_OFF + m2] = (float)ii;
        atomicAdd(&hist[ii], 1);
    }
    __syncthreads();
    const int w = tid >> 6, l = tid & 63;
    for (int wc = 0; wc < 4; ++wc) {
#pragma unroll
        for (int rr = 0; rr < 16; ++rr) {
            const int row = w * 16 + rr;
            const float2 v = *(const float2*)(cb + (size_t)sidx[row] * WIDTH + wc * 128 + l * 2);
            *(float2*)&tile[row][l * 2] = v;
        }
        __syncthreads();
#pragma unroll 8
        for (int wwi = 0; wwi < 32; ++wwi) {
            const int ww = wc * 128 + w * 32 + wwi;
            dout[((size_t)n * WIDTH + ww) * T_DIM + t0 + l] = tile[l][w * 32 + wwi];
        }
        __syncthreads();
    }
}

// perplexity from hist + commit loss = sum(xnorm + s_win) / OUT_ELEMS
__global__ __launch_bounds__(1024) void k_finalize(
    const int* __restrict__ hist, const float* __restrict__ xnorm,
    const float* __restrict__ sbest, float* __restrict__ dout) {
    const int tid = threadIdx.x;
    float e;
    {
        const float p = (float)hist[tid] * (1.0f / (float)M_ROWS);
        e = p * logf(p + 1e-7f);
    }
    float ls = 0.f;
    for (int i = tid; i < M_ROWS; i += 1024) ls += xnorm[i] + sbest[i];
#pragma unroll
    for (int off = 32; off >= 1; off >>= 1) {
        e += __shfl_xor(e, off, 64);
        ls += __shfl_xor(ls, off, 64);
    }
    __shared__ float se[16], sl[16];
    if ((tid & 63) == 0) { se[tid >> 6] = e; sl[tid >> 6] = ls; }
    __syncthreads();
    if (tid == 0) {
        float E = 0.f, L = 0.f;
#pragma unroll
        for (int i = 0; i < 16; ++i) { E += se[i]; L += sl[i]; }
        dout[LOSS_OFF] = L / (float)OUT_ELEMS;
        dout[PERP_OFF] = expf(-E);
    }
}

extern "C" void kernel_launch(void* const* d_in, const int* in_sizes, int n_in,
                              void* d_out, int out_size, void* d_ws, size_t ws_size,
                              hipStream_t stream) {
    const float* x = (const float*)d_in[0];
    const float* cb = (const float*)d_in[1];
    float* dout = (float*)d_out;
    uint8_t* w = (uint8_t*)d_ws;

    unsigned short* cbh = (unsigned short*)w;                        // 1 MB
    float* cnorm   = (float*)(w + (1u << 20));                       // 4 KB
    int*   hist    = (int*)(w + (1u << 20) + 4096);                  // 4 KB
    uint32_t* cand = (uint32_t*)(w + (1u << 20) + 8192);             // 256 KB
    int* idx_final = (int*)(w + (1u << 20) + 8192 + 262144);         // 256 KB
    float* sbest   = (float*)(w + (1u << 20) + 8192 + 2 * 262144);   // 256 KB
    float* xnorm   = (float*)(w + (1u << 20) + 8192 + 3 * 262144);   // 256 KB

    unsigned short* xTh = (unsigned short*)d_out;                    // 64 MiB scratch

    k_prep<<<NB_CODE, 128, 0, stream>>>(cb, cbh, cnorm, hist);
    k_xprep<<<dim3(T_DIM / 32, N_BATCH), 256, 0, stream>>>(x, xTh, xnorm);
    k_argmin<<<M_ROWS / 256, 512, 0, stream>>>(xTh, cbh, cnorm, cand, sbest);
    k_rescore<<<1024, 256, 0, stream>>>(x, cb, cnorm, cand, idx_final, sbest);
    k_scatter<<<1024, 256, 0, stream>>>(cb, idx_final, dout, hist);
    k_finalize<<<1, 1024, 0, stream>>>(hist, xnorm, sbest, dout);
}

// Round 9
// 199.192 us; speedup vs baseline: 1.5910x; 1.1162x over previous
//
#include <hip/hip_runtime.h>
#include <cstddef>
#include <cstdint>

#define N_BATCH 32
#define WIDTH   512
#define T_DIM   2048
#define NB_CODE 1024
#define M_ROWS  65536
#define OUT_ELEMS 33554432
#define IDX_OFF  OUT_ELEMS
#define LOSS_OFF (OUT_ELEMS + M_ROWS)
#define PERP_OFF (LOSS_OFF + 1)
#define MARGIN   0.75f

typedef __attribute__((ext_vector_type(8))) short vshort8;
typedef __attribute__((ext_vector_type(4))) float vfloat4;
typedef __attribute__((ext_vector_type(16))) float vfloat16;

typedef __attribute__((address_space(1))) const uint32_t gu32_t;
typedef __attribute__((address_space(3))) uint32_t lu32_t;
static __device__ __forceinline__ void gload16(const void* g, void* l) {
    __builtin_amdgcn_global_load_lds((gu32_t*)g, (lu32_t*)l, 16, 0, 0);
}

static __device__ __forceinline__ unsigned short f2bf(float f) {
    uint32_t u = __float_as_uint(f);
    uint32_t r = (u + 0x7FFFu + ((u >> 16) & 1u)) >> 16;  // RNE
    return (unsigned short)r;
}
static __device__ __forceinline__ float bf2f(unsigned short s) {
    return __uint_as_float(((uint32_t)s) << 16);
}

// ---------------- workspace layout (bytes) ----------------
// cbh 1MB | cnorm 4K | hist 4K | cand 256K | idx 256K | sbest 256K | xnorm 256K

// bf16 codebook + per-code norms + hist zeroing.
__global__ __launch_bounds__(128) void k_prep(const float* __restrict__ cb,
                                              unsigned short* __restrict__ cbh,
                                              float* __restrict__ cnorm,
                                              int* __restrict__ hist) {
    const int c = blockIdx.x, tid = threadIdx.x;
    float4 v = ((const float4*)(cb + (size_t)c * WIDTH))[tid];
    ushort4 h;
    h.x = f2bf(v.x); h.y = f2bf(v.y); h.z = f2bf(v.z); h.w = f2bf(v.w);
    ((ushort4*)(cbh + (size_t)c * WIDTH))[tid] = h;
    float s = v.x * v.x + v.y * v.y + v.z * v.z + v.w * v.w;
#pragma unroll
    for (int off = 32; off >= 1; off >>= 1) s += __shfl_xor(s, off, 64);
    __shared__ float sw[2];
    if ((tid & 63) == 0) sw[tid >> 6] = s;
    __syncthreads();
    if (tid == 0) { cnorm[c] = sw[0] + sw[1]; hist[c] = 0; }
}

// hh-screen argmin, 32x32x16 MFMA, FUSED x load/convert (no xprep pass).
// 512 thr = 8 waves, 256 rows/block, 32 rows/wave (x full-K in regs via
// coalesced f32 loads + v_cvt_pk_bf16_f32; exact fp32 row norms inline).
// Codebook streamed in 16 chunks of 64 codes x 512 k (64KB), double-buffered;
// ONE barrier + ONE vmcnt(0) per chunk. LDS [kb][code][128 bf16] with
// ^((code&15)<<4) swizzle -> 2-way (free).
__global__ __launch_bounds__(512, 2) void k_argmin(
    const float* __restrict__ x, const unsigned short* __restrict__ cbh,
    const float* __restrict__ cnorm, uint32_t* __restrict__ cand,
    float* __restrict__ sbest, float* __restrict__ xnorm) {
    __shared__ __align__(16) short lds[2][32768];   // 2 x 64KB
    __shared__ __align__(16) float cns[NB_CODE];

    const int tid = threadIdx.x;
    const int wv = tid >> 6, l = tid & 63;
    const int l31 = l & 31, hi = l >> 5;
    const int m = l31 & 15;

    // staging source offsets (inverse swizzle), lds linear slot q = wv*512+j*64+l
    int srcoff[8];
#pragma unroll
    for (int j = 0; j < 8; ++j) {
        const int q = wv * 512 + j * 64 + l;
        const int kb = q >> 10, code = (q >> 4) & 63, s = q & 15;
        srcoff[j] = code * 1024 + kb * 256 + ((s ^ (code & 15)) << 4);
    }

#define STAGE(SP, B) do {                                                     \
    const char* cbbase_ = ((const char*)cbh) + (SP) * 65536;                  \
    short* lb_ = &lds[B][0];                                                  \
    _Pragma("unroll")                                                         \
    for (int j = 0; j < 8; ++j)                                               \
        gload16(cbbase_ + srcoff[j], lb_ + (wv * 512 + j * 64) * 8);          \
} while (0)

    STAGE(0, 0);

    { ((float2*)cns)[tid] = ((const float2*)cnorm)[tid]; }

    // ---- fused x load: 32 rows/wave, coalesced f32 (lane=t), cvt_pk to bf16.
    // lane covers k = ks*16 + hi*8 + e; 32 lanes x 4B = 128B contiguous per k.
    const int m0w = blockIdx.x * 256 + wv * 32;
    const int n = m0w >> 11;
    const int tcol = (m0w & 2047) + l31;
    vshort8 xh[32];
    float xn = 0.f;
    {
        const float* xb = x + (size_t)n * WIDTH * T_DIM + (size_t)hi * 8 * T_DIM + tcol;
        union U8 { uint32_t u[4]; vshort8 v; };
#pragma unroll
        for (int ks = 0; ks < 32; ++ks) {
            U8 u;
#pragma unroll
            for (int j = 0; j < 4; ++j) {
                const float f0 = xb[(size_t)(ks * 16 + 2 * j) * T_DIM];
                const float f1 = xb[(size_t)(ks * 16 + 2 * j + 1) * T_DIM];
                xn = fmaf(f0, f0, fmaf(f1, f1, xn));
                asm("v_cvt_pk_bf16_f32 %0, %1, %2" : "=v"(u.u[j]) : "v"(f0), "v"(f1));
            }
            xh[ks] = u.v;
        }
    }
    xn += __shfl_xor(xn, 32, 64);
    if (l < 32) xnorm[m0w + l] = xn;   // exact fp32 row norm

    // swizzled ds_read base (shorts): row=tl*32+l31 (256B rows), slot XOR
    const int B34 = (m >> 1) << 4;
    const int base_s = l31 * 128 + ((hi ^ (m & 1)) << 3);

    float b1 = 3.4e38f, b2 = 3.4e38f, b3 = 3.4e38f;
    int i1 = 0, i2 = 0, i3 = 0;

#define INS3(S, C) do {                                                       \
        const bool lt1 = (S) < b1, lt2 = (S) < b2, lt3 = (S) < b3;            \
        b3 = lt3 ? (lt2 ? b2 : (S)) : b3;  i3 = lt3 ? (lt2 ? i2 : (C)) : i3; \
        b2 = lt2 ? (lt1 ? b1 : (S)) : b2;  i2 = lt2 ? (lt1 ? i1 : (C)) : i2; \
        b1 = lt1 ? (S) : b1;               i1 = lt1 ? (C) : i1;              \
    } while (0)

    __syncthreads();   // full drain: chunk0, cns, x loads

    for (int sp = 0; sp < 16; ++sp) {
        if (sp) {
            asm volatile("s_waitcnt vmcnt(0)" ::: "memory");  // own STAGE(sp) done
            __builtin_amdgcn_s_barrier();                     // everyone's done
        }
        if (sp < 15) {
            if (sp & 1) STAGE(sp + 1, 0); else STAGE(sp + 1, 1);
        }
        const short* buf = lds[sp & 1];
        vfloat16 acc0 = {}, acc1 = {};
        __builtin_amdgcn_s_setprio(1);
#pragma unroll
        for (int ks = 0; ks < 32; ++ks) {
            const int koff = ((ks >> 3) << 13) + (((ks & 7) << 4) ^ B34);
            vshort8 a0 = *(const vshort8*)&buf[base_s + koff];
            acc0 = __builtin_amdgcn_mfma_f32_32x32x16_bf16(a0, xh[ks], acc0, 0, 0, 0);
            vshort8 a1 = *(const vshort8*)&buf[base_s + koff + 4096];
            acc1 = __builtin_amdgcn_mfma_f32_32x32x16_bf16(a1, xh[ks], acc1, 0, 0, 0);
        }
        __builtin_amdgcn_s_setprio(0);
        // score 64 codes: D[code][xrow], col=lane&31=row, code=(r&3)+8*(r>>2)+4*hi
        const int cb0 = sp * 64;
#pragma unroll
        for (int tl = 0; tl < 2; ++tl) {
#pragma unroll
            for (int g = 0; g < 4; ++g) {
                const int cbase = cb0 + tl * 32 + g * 8 + 4 * hi;
                vfloat4 cn = *(const vfloat4*)&cns[cbase];
#pragma unroll
                for (int j = 0; j < 4; ++j) {
                    const float a = tl ? acc1[g * 4 + j] : acc0[g * 4 + j];
                    const float s = fmaf(-2.f, a, cn[j]);
                    INS3(s, cbase + j);
                }
            }
        }
    }

    // merge top-3 across the hi halves (disjoint code sets)
    {
        const float ob1 = __shfl_xor(b1, 32, 64), ob2 = __shfl_xor(b2, 32, 64), ob3 = __shfl_xor(b3, 32, 64);
        const int oi1 = __shfl_xor(i1, 32, 64), oi2 = __shfl_xor(i2, 32, 64), oi3 = __shfl_xor(i3, 32, 64);
        INS3(ob1, oi1); INS3(ob2, oi2); INS3(ob3, oi3);
    }
    if (l < 32) {
        const uint32_t f2 = (b2 - b1 < MARGIN) ? 1u : 0u;
        const uint32_t f3 = (b3 - b1 < MARGIN) ? 1u : 0u;
        cand[m0w + l] = (uint32_t)i1 | ((uint32_t)i2 << 10) | ((uint32_t)i3 << 20) | (f2 << 30) | (f3 << 31);
        sbest[m0w + l] = b1;   // screen-score of winner (overwritten if rescored)
    }
}

// EXACT fp32 rescore of flagged rows (original x + fp32 cb), one wave/row.
// Writes final idx + exact winning score.
__global__ __launch_bounds__(256) void k_rescore(
    const float* __restrict__ x, const float* __restrict__ cb,
    const float* __restrict__ cnorm, const uint32_t* __restrict__ cand,
    int* __restrict__ idx_final, float* __restrict__ sbest) {
    __shared__ int list[64];
    __shared__ int cnt;
    const int tid = threadIdx.x;
    const int m0 = blockIdx.x * 64;
    if (tid == 0) cnt = 0;
    __syncthreads();
    if (tid < 64) {
        const uint32_t wv = cand[m0 + tid];
        if (wv >> 30) { const int p = atomicAdd(&cnt, 1); list[p] = tid; }
        else idx_final[m0 + tid] = (int)(wv & 1023u);
    }
    __syncthreads();
    const int nf = cnt;
    const int w = tid >> 6, lid = tid & 63;
    for (int it = w; it < nf; it += 4) {
        const int row = m0 + list[it];
        const uint32_t wv = cand[row];
        const int j1 = (int)(wv & 1023u), j2 = (int)((wv >> 10) & 1023u), j3 = (int)((wv >> 20) & 1023u);
        const bool nd3 = (wv >> 31) & 1u;
        const int n = row >> 11, t = row & 2047;
        const float* xc = x + (size_t)n * WIDTH * T_DIM + t;
        float xv[8];
#pragma unroll
        for (int e = 0; e < 8; ++e)
            xv[e] = xc[(size_t)(lid * 8 + e) * T_DIM];
        float d1 = 0.f, d2 = 0.f, d3 = 0.f;
        {
            const float* c1 = cb + (size_t)j1 * WIDTH + lid * 8;
            const float* c2 = cb + (size_t)j2 * WIDTH + lid * 8;
            const float* c3 = cb + (size_t)j3 * WIDTH + lid * 8;
            float4 a0 = *(const float4*)c1, a1 = *(const float4*)(c1 + 4);
            d1 = fmaf(xv[0], a0.x, fmaf(xv[1], a0.y, fmaf(xv[2], a0.z, fmaf(xv[3], a0.w,
                 fmaf(xv[4], a1.x, fmaf(xv[5], a1.y, fmaf(xv[6], a1.z, xv[7] * a1.w)))))));
            float4 b0 = *(const float4*)c2, b1v = *(const float4*)(c2 + 4);
            d2 = fmaf(xv[0], b0.x, fmaf(xv[1], b0.y, fmaf(xv[2], b0.z, fmaf(xv[3], b0.w,
                 fmaf(xv[4], b1v.x, fmaf(xv[5], b1v.y, fmaf(xv[6], b1v.z, xv[7] * b1v.w)))))));
            if (nd3) {
                float4 g0 = *(const float4*)c3, g1 = *(const float4*)(c3 + 4);
                d3 = fmaf(xv[0], g0.x, fmaf(xv[1], g0.y, fmaf(xv[2], g0.z, fmaf(xv[3], g0.w,
                     fmaf(xv[4], g1.x, fmaf(xv[5], g1.y, fmaf(xv[6], g1.z, xv[7] * g1.w)))))));
            }
        }
#pragma unroll
        for (int off = 32; off >= 1; off >>= 1) {
            d1 += __shfl_xor(d1, off, 64);
            d2 += __shfl_xor(d2, off, 64);
            d3 += __shfl_xor(d3, off, 64);
        }
        if (lid == 0) {
            int win = j1;
            float qw = fmaf(-2.f, d1, cnorm[j1]);
            const float q2 = fmaf(-2.f, d2, cnorm[j2]);
            if (q2 < qw || (q2 == qw && j2 < win)) { win = j2; qw = q2; }
            if (nd3) {
                const float q3 = fmaf(-2.f, d3, cnorm[j3]);
                if (q3 < qw || (q3 == qw && j3 < win)) { win = j3; qw = q3; }
            }
            idx_final[row] = win;
            sbest[row] = qw;
        }
    }
}

// Gather codebook[idx] -> out [N][W][T] via LDS transpose staging,
// idx as float, histogram. (No x reads -- loss comes from the dist identity.)
__global__ __launch_bounds__(256) void k_scatter(
    const float* __restrict__ cb, const int* __restrict__ idx,
    float* __restrict__ dout, int* __restrict__ hist) {
    __shared__ int sidx[64];
    __shared__ float tile[64][130];
    const int tid = threadIdx.x;
    const int b = blockIdx.x;
    const int n = b >> 5;
    const int t0 = (b & 31) * 64;
    if (tid < 64) {
        const int m2 = n * T_DIM + t0 + tid;
        const int ii = idx[m2];
        sidx[tid] = ii;
        dout[IDX_OFF + m2] = (float)ii;
        atomicAdd(&hist[ii], 1);
    }
    __syncthreads();
    const int w = tid >> 6, l = tid & 63;
    for (int wc = 0; wc < 4; ++wc) {
#pragma unroll
        for (int rr = 0; rr < 16; ++rr) {
            const int row = w * 16 + rr;
            const float2 v = *(const float2*)(cb + (size_t)sidx[row] * WIDTH + wc * 128 + l * 2);
            *(float2*)&tile[row][l * 2] = v;
        }
        __syncthreads();
#pragma unroll 8
        for (int wwi = 0; wwi < 32; ++wwi) {
            const int ww = wc * 128 + w * 32 + wwi;
            dout[((size_t)n * WIDTH + ww) * T_DIM + t0 + l] = tile[l][w * 32 + wwi];
        }
        __syncthreads();
    }
}

// perplexity from hist + commit loss = sum(xnorm + s_win) / OUT_ELEMS
__global__ __launch_bounds__(1024) void k_finalize(
    const int* __restrict__ hist, const float* __restrict__ xnorm,
    const float* __restrict__ sbest, float* __restrict__ dout) {
    const int tid = threadIdx.x;
    float e;
    {
        const float p = (float)hist[tid] * (1.0f / (float)M_ROWS);
        e = p * logf(p + 1e-7f);
    }
    float ls = 0.f;
    for (int i = tid; i < M_ROWS; i += 1024) ls += xnorm[i] + sbest[i];
#pragma unroll
    for (int off = 32; off >= 1; off >>= 1) {
        e += __shfl_xor(e, off, 64);
        ls += __shfl_xor(ls, off, 64);
    }
    __shared__ float se[16], sl[16];
    if ((tid & 63) == 0) { se[tid >> 6] = e; sl[tid >> 6] = ls; }
    __syncthreads();
    if (tid == 0) {
        float E = 0.f, L = 0.f;
#pragma unroll
        for (int i = 0; i < 16; ++i) { E += se[i]; L += sl[i]; }
        dout[LOSS_OFF] = L / (float)OUT_ELEMS;
        dout[PERP_OFF] = expf(-E);
    }
}

extern "C" void kernel_launch(void* const* d_in, const int* in_sizes, int n_in,
                              void* d_out, int out_size, void* d_ws, size_t ws_size,
                              hipStream_t stream) {
    const float* x = (const float*)d_in[0];
    const float* cb = (const float*)d_in[1];
    float* dout = (float*)d_out;
    uint8_t* w = (uint8_t*)d_ws;

    unsigned short* cbh = (unsigned short*)w;                        // 1 MB
    float* cnorm   = (float*)(w + (1u << 20));                       // 4 KB
    int*   hist    = (int*)(w + (1u << 20) + 4096);                  // 4 KB
    uint32_t* cand = (uint32_t*)(w + (1u << 20) + 8192);             // 256 KB
    int* idx_final = (int*)(w + (1u << 20) + 8192 + 262144);         // 256 KB
    float* sbest   = (float*)(w + (1u << 20) + 8192 + 2 * 262144);   // 256 KB
    float* xnorm   = (float*)(w + (1u << 20) + 8192 + 3 * 262144);   // 256 KB

    k_prep<<<NB_CODE, 128, 0, stream>>>(cb, cbh, cnorm, hist);
    k_argmin<<<M_ROWS / 256, 512, 0, stream>>>(x, cbh, cnorm, cand, sbest, xnorm);
    k_rescore<<<1024, 256, 0, stream>>>(x, cb, cnorm, cand, idx_final, sbest);
    k_scatter<<<1024, 256, 0, stream>>>(cb, idx_final, dout, hist);
    k_finalize<<<1, 1024, 0, stream>>>(hist, xnorm, sbest, dout);
}